// Round 1
// baseline (807.877 us; speedup 1.0000x reference)
//
#include <hip/hip_runtime.h>

// CorrelationLayer cost volume, fp32 baseline.
// out[b, di*21+dj, y, x] = sum_c L[b,c,y,x] * R[b,c, y-j, x-i],
//   i = -20 + 2*di (x-shift), j = -20 + 2*dj (y-shift), zero-padded.
//
// Block = (b, y1, dj-quad of 4). 128 threads = 2 waves.
// Lane map: xt = lane&7 (owns x0=8*xt..x0+7), g = (lane>>3)&3 (di group 6g..6g+5),
//           h = lane>>5; rsel = wave*2 + h selects which dj of the quad.
// LDS: L row chunk [CB][64] + 4 zero-padded R row chunks [CB][112]
//   (Rpad[r][c][p] = R[c][p-28]; pads stay zero so shifts never branch).
// Per channel: 2+5 ds_read_b128 -> 48 FMAs per lane (register window reuse).

namespace {
constexpr int Bn = 32, Cn = 256, Hn = 48, Wn = 64;
constexpr int ND  = 21;            // displacements per axis
constexpr int NDD = ND * ND;       // 441
constexpr int NQ  = 6;             // dj quads per (b,y1): 6*4 = 24 slots, 3 dead
constexpr int CB  = 8;             // channel chunk
constexpr int PADW = 112;          // padded R row width
constexpr int POFF = 28;           // Rpad[p] = R[p - POFF]
constexpr int NBLK = Bn * Hn * NQ; // 9216
}

__global__ __launch_bounds__(128, 4)
void corr_fp32(const float* __restrict__ Lp, const float* __restrict__ Rp,
               float* __restrict__ out)
{
    // XCD-aware chunked swizzle (bijective: NBLK % 8 == 0).
    constexpr int CPX = NBLK / 8;
    const int bid = blockIdx.x;
    const int lb  = (bid & 7) * CPX + (bid >> 3);

    // lb = ((b*6 + yt)*8 + yi)*NQ + q ; y1 = yt*8 + yi  (locality: q, then y within tile)
    const int q  = lb % NQ;
    const int r0 = lb / NQ;
    const int yi = r0 & 7;
    const int r1 = r0 >> 3;
    const int yt = r1 % 6;
    const int b  = r1 / 6;
    const int y1 = yt * 8 + yi;

    const int tid  = threadIdx.x;
    const int lane = tid & 63;
    const int wv   = tid >> 6;          // wave 0/1
    const int xt   = lane & 7;
    const int g    = (lane >> 3) & 3;
    const int h    = lane >> 5;
    const int x0   = xt * 8;
    const int rsel = wv * 2 + h;        // which dj of the quad this lane computes
    const int dj0  = q * 4;
    const int dj   = dj0 + rsel;
    const int di0  = g * 6;
    const int wb   = x0 + 36 - 12 * g;  // window base (16B aligned), offsets e+12-2k in [2,19]

    int  y2s[4]; bool rvv[4]; bool any = false;
#pragma unroll
    for (int r = 0; r < 4; ++r) {
        const int djr = dj0 + r;
        const int y2  = y1 + 20 - 2 * djr;   // y2 = y1 - j
        const bool v  = (djr < ND) && (y2 >= 0) && (y2 < Hn);
        y2s[r] = y2; rvv[r] = v; any |= v;
    }

    if (!any) {
        // whole quad out of range: zero-fill owned outputs and exit
        for (int s = tid; s < ND * 4 * Wn; s += 128) {
            const int x   = s & (Wn - 1);
            const int r2  = s >> 6;
            const int r   = r2 & 3;
            const int di  = r2 >> 2;
            const int djr = dj0 + r;
            if (djr < ND)
                out[(((size_t)b * NDD + (size_t)(di * ND + djr)) * Hn + y1) * Wn + x] = 0.f;
        }
        return;
    }

    __shared__ float Lrow[CB][Wn];
    __shared__ float Rpad[4][CB][PADW];

    // zero once: pads persist; invalid rows stay all-zero (their acc -> correct zeros)
    for (int s = tid; s < 4 * CB * PADW; s += 128)
        (&Rpad[0][0][0])[s] = 0.f;

    float acc[6][8];
#pragma unroll
    for (int k = 0; k < 6; ++k)
#pragma unroll
        for (int e = 0; e < 8; ++e) acc[k][e] = 0.f;

    const int cst = tid >> 4;          // 0..7   staging: channel within chunk
    const int xq  = (tid & 15) * 4;    // 0..60  staging: x quad

    for (int cc = 0; cc < Cn; cc += CB) {
        __syncthreads();   // protect LDS overwrite vs previous chunk's reads (and zero-init)
        {
            const size_t rowL = (((size_t)b * Cn + cc + cst) * Hn + y1) * (size_t)Wn + xq;
            const float4 lv4 = *(const float4*)&Lp[rowL];
            *(float4*)&Lrow[cst][xq] = lv4;
#pragma unroll
            for (int r = 0; r < 4; ++r) {
                if (rvv[r]) {
                    const size_t rowR = (((size_t)b * Cn + cc + cst) * Hn + y2s[r]) * (size_t)Wn + xq;
                    const float4 rv4 = *(const float4*)&Rp[rowR];
                    *(float4*)&Rpad[r][cst][POFF + xq] = rv4;
                }
            }
        }
        __syncthreads();

        const float* rbase = &Rpad[rsel][0][0];
        for (int c = 0; c < CB; ++c) {
            const float4 a0 = *(const float4*)&Lrow[c][x0];
            const float4 a1 = *(const float4*)&Lrow[c][x0 + 4];
            const float lv[8] = { a0.x, a0.y, a0.z, a0.w, a1.x, a1.y, a1.z, a1.w };

            const float4 w0 = *(const float4*)&rbase[c * PADW + wb +  0];
            const float4 w1 = *(const float4*)&rbase[c * PADW + wb +  4];
            const float4 w2 = *(const float4*)&rbase[c * PADW + wb +  8];
            const float4 w3 = *(const float4*)&rbase[c * PADW + wb + 12];
            const float4 w4 = *(const float4*)&rbase[c * PADW + wb + 16];
            const float wvw[20] = { w0.x, w0.y, w0.z, w0.w, w1.x, w1.y, w1.z, w1.w,
                                    w2.x, w2.y, w2.z, w2.w, w3.x, w3.y, w3.z, w3.w,
                                    w4.x, w4.y, w4.z, w4.w };
#pragma unroll
            for (int k = 0; k < 6; ++k)
#pragma unroll
                for (int e = 0; e < 8; ++e)
                    acc[k][e] = fmaf(lv[e], wvw[e + 12 - 2 * k], acc[k][e]);
        }
    }

    if (dj < ND) {
#pragma unroll
        for (int k = 0; k < 6; ++k) {
            const int di = di0 + k;
            if (di < ND) {
                const size_t o = (((size_t)b * NDD + (size_t)(di * ND + dj)) * Hn + y1) * (size_t)Wn + x0;
                *(float4*)&out[o]     = make_float4(acc[k][0], acc[k][1], acc[k][2], acc[k][3]);
                *(float4*)&out[o + 4] = make_float4(acc[k][4], acc[k][5], acc[k][6], acc[k][7]);
            }
        }
    }
}

extern "C" void kernel_launch(void* const* d_in, const int* /*in_sizes*/, int /*n_in*/,
                              void* d_out, int /*out_size*/, void* /*d_ws*/, size_t /*ws_size*/,
                              hipStream_t stream)
{
    const float* l = (const float*)d_in[0];   // conv3_pool_l
    const float* r = (const float*)d_in[1];   // conv3_pool_r
    float* o = (float*)d_out;
    corr_fp32<<<NBLK, 128, 0, stream>>>(l, r, o);
}

// Round 8
// 383.124 us; speedup vs baseline: 2.1087x; 2.1087x over previous
//
#include <hip/hip_runtime.h>

// Cost volume via banded Gram MFMA (fp16 inputs, fp32 accumulate).
// out[b, di*21+dj, y1, x] = sum_c L[b,c,y1,x] * R[b,c,y2,x'],
//   y2 = y1 - j (j = 2*(dj-10)... j = y1-y2 -> dj = y1h-y2h+10), x' = x - i,
//   i = 2*(di-10) = 2*(xe-xe') with x = 2*xe+p (x-parity p).
// Per (b, y-parity yq, y1-pair g, y2-quad z): waves (p, zp) compute
// 32x32 Gram tiles G_p[xe,xe'] with mfma_f32_32x32x16_f16 over K=256.
// Epilogue transposes G through LDS into coalesced 64-float out rows,
// zero-filling x-clip and invalid-y2 so every out element is written once.
//
// k-map note: A and B are staged via the identical LDS layout + fk formula,
// and Gram accumulation is invariant under any lane/reg->k permutation
// applied equally to both operands — only the C/D map (HW-verified
// m74/m101) must be exact.

typedef _Float16 f16;
typedef f16 f16x8 __attribute__((ext_vector_type(8)));
typedef float f32x16 __attribute__((ext_vector_type(16)));

namespace {
constexpr int ND  = 21;
constexpr int HW  = 48 * 64;           // 3072 floats per (b,c) plane
constexpr int RP  = 24;                // fp16 k-row: 16 data + 8 pad (48 B)
constexpr int NBLK = 4608;             // 32 b * 2 yq * 12 g * 6 zz
}

static __device__ __forceinline__ unsigned pk2(float a, float b) {
  unsigned short lo = __builtin_bit_cast(unsigned short, (_Float16)a);
  unsigned short hi = __builtin_bit_cast(unsigned short, (_Float16)b);
  return (unsigned)lo | ((unsigned)hi << 16);
}
static __device__ __forceinline__ f16x8 mk8(float a0, float a1, float a2, float a3,
                                            float a4, float a5, float a6, float a7) {
  union { f16x8 v; unsigned u[4]; } r;
  r.u[0] = pk2(a0, a1); r.u[1] = pk2(a2, a3);
  r.u[2] = pk2(a4, a5); r.u[3] = pk2(a6, a7);
  return r.v;
}

__global__ __launch_bounds__(256, 3)
void corr_mfma(const float* __restrict__ L, const float* __restrict__ R,
               float* __restrict__ out)
{
  __shared__ __align__(16) f16   Ash[2 * 2 * 32 * RP];  // [p][yi][xe][RP]
  __shared__ __align__(16) f16   Bsh[2 * 4 * 32 * RP];  // [p][zi][xe][RP]
  __shared__ __align__(16) float Epi[4 * 21 * 68];      // [zi][di][x pad68]

  // XCD-chunked bijective swizzle (4608 % 8 == 0): one (b,yq) per XCD at a time.
  const int bid = blockIdx.x;
  const int lb  = (bid & 7) * (NBLK / 8) + (bid >> 3);
  const int b   = lb / 144;
  int rr_ = lb - b * 144;
  const int yq = rr_ / 72;  rr_ -= yq * 72;
  const int g  = rr_ / 6;
  const int zz = rr_ - g * 6;
  const int z  = (2 * g + 54) / 4 - 16 + zz;   // floor((2g-10)/4) + zz

  const int tid  = threadIdx.x;
  const int lane = tid & 63;
  const int wv   = tid >> 6;       // 4 waves
  const int p    = wv & 1;         // x-parity of this wave
  const int zp   = wv >> 1;        // y2-pair of this wave

  int  y1row[2], y2row[4], dj_[2][4];
  bool zval[4], pv[2][4];
#pragma unroll
  for (int yi = 0; yi < 2; ++yi) y1row[yi] = 4 * g + 2 * yi + yq;
#pragma unroll
  for (int zi = 0; zi < 4; ++zi) {
    const int y2h = 4 * z + zi;
    zval[zi]  = (y2h >= 0) && (y2h < 24);
    y2row[zi] = 2 * y2h + yq;
#pragma unroll
    for (int yi = 0; yi < 2; ++yi) {
      const int dj = (2 * g + yi) - y2h + 10;
      dj_[yi][zi] = dj;
      pv[yi][zi]  = (dj >= 0) && (dj <= 20);
    }
  }
  const bool tv00 = pv[0][2*zp]   && zval[2*zp];
  const bool tv01 = pv[0][2*zp+1] && zval[2*zp+1];
  const bool tv10 = pv[1][2*zp]   && zval[2*zp];
  const bool tv11 = pv[1][2*zp+1] && zval[2*zp+1];

  // ---- staging task: t<64 -> A (L, 2 rows), 64<=t<192 -> B (R, 4 rows) ----
  const float* gsrc = nullptr;
  f16 *dp0 = nullptr, *dp1 = nullptr, *dp2 = nullptr, *dp3 = nullptr;
  if (tid < 64) {
    const int row = tid >> 5, c8 = (tid >> 4) & 1, xq4 = tid & 15;
    gsrc = L + (size_t)b * (256 * HW) + (size_t)(8 * c8) * HW
             + y1row[row] * 64 + xq4 * 4;
    const int xe = 2 * xq4;
    dp0 = &Ash[((0 * 2 + row) * 32 + xe    ) * RP + 8 * c8];
    dp1 = &Ash[((1 * 2 + row) * 32 + xe    ) * RP + 8 * c8];
    dp2 = &Ash[((0 * 2 + row) * 32 + xe + 1) * RP + 8 * c8];
    dp3 = &Ash[((1 * 2 + row) * 32 + xe + 1) * RP + 8 * c8];
  } else if (tid < 192) {
    const int u = tid - 64, zi = u >> 5, c8 = (u >> 4) & 1, xq4 = u & 15;
    if (zval[zi])
      gsrc = R + (size_t)b * (256 * HW) + (size_t)(8 * c8) * HW
               + y2row[zi] * 64 + xq4 * 4;
    const int xe = 2 * xq4;
    dp0 = &Bsh[((0 * 4 + zi) * 32 + xe    ) * RP + 8 * c8];
    dp1 = &Bsh[((1 * 4 + zi) * 32 + xe    ) * RP + 8 * c8];
    dp2 = &Bsh[((0 * 4 + zi) * 32 + xe + 1) * RP + 8 * c8];
    dp3 = &Bsh[((1 * 4 + zi) * 32 + xe + 1) * RP + 8 * c8];
  }

  // ---- MFMA fragment pointers (constant across chunks) ----
  const int fxe = lane & 31;
  const int fk  = (lane >> 5) * 8;     // A/B k-map: k = 8*(lane>>5)+j
  const f16* fa0p = &Ash[((p * 2 + 0) * 32 + fxe) * RP + fk];
  const f16* fa1p = &Ash[((p * 2 + 1) * 32 + fxe) * RP + fk];
  const f16* fb0p = &Bsh[((p * 4 + 2 * zp    ) * 32 + fxe) * RP + fk];
  const f16* fb1p = &Bsh[((p * 4 + 2 * zp + 1) * 32 + fxe) * RP + fk];

  f32x16 acc00{}, acc01{}, acc10{}, acc11{};
  float4 pf0, pf1, pf2, pf3, pf4, pf5, pf6, pf7;

  auto loadch = [&](int ch) {
    if (gsrc) {
      const float* s = gsrc + (size_t)ch * 16 * HW;
      pf0 = *(const float4*)(s);
      pf1 = *(const float4*)(s + 1 * HW);
      pf2 = *(const float4*)(s + 2 * HW);
      pf3 = *(const float4*)(s + 3 * HW);
      pf4 = *(const float4*)(s + 4 * HW);
      pf5 = *(const float4*)(s + 5 * HW);
      pf6 = *(const float4*)(s + 6 * HW);
      pf7 = *(const float4*)(s + 7 * HW);
    }
  };

  loadch(0);
  for (int ch = 0; ch < 16; ++ch) {
    __syncthreads();                          // previous chunk's reads done
    if (gsrc) {
      f16x8 w0 = mk8(pf0.x, pf1.x, pf2.x, pf3.x, pf4.x, pf5.x, pf6.x, pf7.x);
      f16x8 w1 = mk8(pf0.y, pf1.y, pf2.y, pf3.y, pf4.y, pf5.y, pf6.y, pf7.y);
      f16x8 w2 = mk8(pf0.z, pf1.z, pf2.z, pf3.z, pf4.z, pf5.z, pf6.z, pf7.z);
      f16x8 w3 = mk8(pf0.w, pf1.w, pf2.w, pf3.w, pf4.w, pf5.w, pf6.w, pf7.w);
      *(f16x8*)dp0 = w0;   // e=0: p=0, xe
      *(f16x8*)dp1 = w1;   // e=1: p=1, xe
      *(f16x8*)dp2 = w2;   // e=2: p=0, xe+1
      *(f16x8*)dp3 = w3;   // e=3: p=1, xe+1
    }
    __syncthreads();                          // LDS chunk ready
    if (ch + 1 < 16) loadch(ch + 1);          // prefetch next chunk (hidden)

    const f16x8 fa0 = *(const f16x8*)fa0p;
    const f16x8 fa1 = *(const f16x8*)fa1p;
    const f16x8 fb0 = *(const f16x8*)fb0p;
    const f16x8 fb1 = *(const f16x8*)fb1p;
    if (tv00) acc00 = __builtin_amdgcn_mfma_f32_32x32x16_f16(fa0, fb0, acc00, 0, 0, 0);
    if (tv01) acc01 = __builtin_amdgcn_mfma_f32_32x32x16_f16(fa0, fb1, acc01, 0, 0, 0);
    if (tv10) acc10 = __builtin_amdgcn_mfma_f32_32x32x16_f16(fa1, fb0, acc10, 0, 0, 0);
    if (tv11) acc11 = __builtin_amdgcn_mfma_f32_32x32x16_f16(fa1, fb1, acc11, 0, 0, 0);
  }

  // ---- epilogue: G tiles -> LDS transpose -> coalesced out rows ----
  __syncthreads();
  for (int i = tid; i < 4 * 21 * 68; i += 256) Epi[i] = 0.f;

  const int nn = lane & 31;
  const int hh = lane >> 5;
  const size_t ob = (size_t)b * (441 * HW);

#pragma unroll
  for (int yi = 0; yi < 2; ++yi) {
    __syncthreads();   // zero-fill done / previous round's stores done
    // dump: C/D layout col=lane&31, row=(r&3)+8*(r>>2)+4*(lane>>5)  [m74/m101]
    {
      const f32x16& A0 = yi ? acc10 : acc00;
      const f32x16& A1 = yi ? acc11 : acc01;
      if (pv[yi][2 * zp]) {
        const int zi = 2 * zp;
#pragma unroll
        for (int r = 0; r < 16; ++r) {
          const int m  = (r & 3) + 8 * (r >> 2) + 4 * hh;
          const int di = m - nn + 10;
          if (di >= 0 && di <= 20)
            Epi[zi * 1428 + di * 68 + 2 * m + p] = A0[r];
        }
      }
      if (pv[yi][2 * zp + 1]) {
        const int zi = 2 * zp + 1;
#pragma unroll
        for (int r = 0; r < 16; ++r) {
          const int m  = (r & 3) + 8 * (r >> 2) + 4 * hh;
          const int di = m - nn + 10;
          if (di >= 0 && di <= 20)
            Epi[zi * 1428 + di * 68 + 2 * m + p] = A1[r];
        }
      }
    }
    __syncthreads();
    // store: 4 pairs * 21 di * 64 x, float4-coalesced
#pragma unroll
    for (int it = 0; it < 6; ++it) {
      const int f4 = tid + it * 256;
      if (f4 < 4 * 21 * 16) {
        const int zi  = f4 / 336;
        const int rem = f4 - zi * 336;
        const int di  = rem >> 4;
        const int xq  = (rem & 15) * 4;
        if (pv[yi][zi]) {
          const float4 v = *(const float4*)&Epi[zi * 1428 + di * 68 + xq];
          *(float4*)&out[ob + (size_t)(di * ND + dj_[yi][zi]) * HW
                         + y1row[yi] * 64 + xq] = v;
        }
      }
    }
  }
}

extern "C" void kernel_launch(void* const* d_in, const int* /*in_sizes*/, int /*n_in*/,
                              void* d_out, int /*out_size*/, void* /*d_ws*/, size_t /*ws_size*/,
                              hipStream_t stream)
{
  const float* l = (const float*)d_in[0];   // conv3_pool_l
  const float* r = (const float*)d_in[1];   // conv3_pool_r
  corr_mfma<<<NBLK, 256, 0, stream>>>(l, r, (float*)d_out);
}